// Round 2
// baseline (11546.795 us; speedup 1.0000x reference)
//
#include <hip/hip_runtime.h>

#define BN_EPS 1e-5f

// ---------------- float4 copy: agg := x ----------------
__global__ __launch_bounds__(256) void copy_kernel(const float* __restrict__ in,
                                                   float* __restrict__ out, int total4) {
    int i = blockIdx.x * 256 + threadIdx.x;
    if (i < total4) ((float4*)out)[i] = ((const float4*)in)[i];
}

// ---------------- edge scatter: agg[dst] += in[src], float4 per thread ----------------
template<int F>
__global__ __launch_bounds__(256) void scatter_kernel(const int* __restrict__ src,
        const int* __restrict__ dst, const float* __restrict__ in,
        float* __restrict__ agg, int E) {
    constexpr int QF = F / 4;
    long long idx = (long long)blockIdx.x * 256 + threadIdx.x;
    if (idx >= (long long)E * QF) return;
    int e = (int)(idx / QF);
    int q = (int)(idx & (QF - 1));
    int s = src[e], d = dst[e];
    const float4 v = *(const float4*)(in + (size_t)s * F + q * 4);
    float* p = agg + (size_t)d * F + q * 4;
    atomicAdd(p + 0, v.x); atomicAdd(p + 1, v.y);
    atomicAdd(p + 2, v.z); atomicAdd(p + 3, v.w);
}

// ---------------- GEMM: Out = relu(A @ W + b), optional column stats ----------------
// A: [N,FIN] f32, W: [FIN,FOUT] f32, Out: [N,FOUT] f32.
// CT = column tile held in LDS (<= 32KB). Block handles columns [c0, c0+CT).
// stats: [2*FOUT] (sum, sumsq of post-relu outputs), pre-zeroed.
template<int FIN, int FOUT, int CT, bool STATS>
__global__ __launch_bounds__(256) void gemm_kernel(const float* __restrict__ A,
        const float* __restrict__ W, const float* __restrict__ bias,
        float* __restrict__ Out, int N, float* __restrict__ stats) {
    constexpr int NCB = FOUT / CT;
    __shared__ float Ws[FIN * CT];
    __shared__ float Bs[CT];
    __shared__ float Ss[STATS ? 2 * CT : 1];
    const int cb = blockIdx.x % NCB;
    const int rb = blockIdx.x / NCB;
    const int c0 = cb * CT;
    for (int i = threadIdx.x; i < FIN * CT; i += 256) {
        int k = i / CT, jj = i & (CT - 1);
        Ws[i] = W[(size_t)k * FOUT + c0 + jj];
    }
    if (threadIdx.x < CT) Bs[threadIdx.x] = bias[c0 + threadIdx.x];
    if (STATS) for (int i = threadIdx.x; i < 2 * CT; i += 256) Ss[i] = 0.0f;
    __syncthreads();

    constexpr int GROUPS = 256 / CT;
    constexpr int RPI = GROUPS * 4;
    const int j = threadIdx.x & (CT - 1);
    const int grp = threadIdx.x / CT;
    const float bj = Bs[j];
    const int RB = gridDim.x / NCB;
    float ls = 0.0f, ls2 = 0.0f;

    for (int base = (rb * GROUPS + grp) * 4; base < N; base += RB * RPI) {
        const float* a = A + (size_t)base * FIN;
        if (base + 4 <= N) {
            float acc0 = bj, acc1 = bj, acc2 = bj, acc3 = bj;
            for (int k = 0; k < FIN; k++) {
                float w = Ws[k * CT + j];
                acc0 = fmaf(a[k],           w, acc0);
                acc1 = fmaf(a[FIN + k],     w, acc1);
                acc2 = fmaf(a[2 * FIN + k], w, acc2);
                acc3 = fmaf(a[3 * FIN + k], w, acc3);
            }
            acc0 = fmaxf(acc0, 0.0f); acc1 = fmaxf(acc1, 0.0f);
            acc2 = fmaxf(acc2, 0.0f); acc3 = fmaxf(acc3, 0.0f);
            float* o = Out + (size_t)base * FOUT + c0 + j;
            o[0] = acc0; o[FOUT] = acc1; o[2 * FOUT] = acc2; o[3 * FOUT] = acc3;
            if (STATS) {
                ls  += acc0 + acc1 + acc2 + acc3;
                ls2 += acc0 * acc0 + acc1 * acc1 + acc2 * acc2 + acc3 * acc3;
            }
        } else {
            for (int r = 0; r < 4 && base + r < N; r++) {
                float acc = bj;
                for (int k = 0; k < FIN; k++)
                    acc = fmaf(a[(size_t)r * FIN + k], Ws[k * CT + j], acc);
                acc = fmaxf(acc, 0.0f);
                Out[(size_t)(base + r) * FOUT + c0 + j] = acc;
                if (STATS) { ls += acc; ls2 += acc * acc; }
            }
        }
    }
    if (STATS) {
        atomicAdd(&Ss[j], ls);
        atomicAdd(&Ss[CT + j], ls2);
        __syncthreads();
        for (int i = threadIdx.x; i < CT; i += 256) {
            atomicAdd(&stats[c0 + i], Ss[i]);
            atomicAdd(&stats[FOUT + c0 + i], Ss[CT + i]);
        }
    }
}

// ---------------- BN apply, float4 per thread ----------------
// !POOL: z[i] = bn(y[i]); also agg[i] = z[i] (next layer's agg init).
//  POOL: atomicAdd into pool[batch[row]].
template<int F, bool POOL>
__global__ __launch_bounds__(256) void bn_kernel(const float* __restrict__ y,
        const float* __restrict__ stats, const float* __restrict__ g,
        const float* __restrict__ be, float* __restrict__ z, float* __restrict__ agg,
        const int* __restrict__ batch, float* __restrict__ pool, int N, float invN) {
    constexpr int QF = F / 4;
    int idx = blockIdx.x * 256 + threadIdx.x;
    if (idx >= N * QF) return;
    int q = idx & (QF - 1);
    int i = idx / QF;
    int j0 = q * 4;
    float4 sc, sh;
    {
        float mu0 = stats[j0 + 0] * invN, mu1 = stats[j0 + 1] * invN;
        float mu2 = stats[j0 + 2] * invN, mu3 = stats[j0 + 3] * invN;
        float v0 = fmaxf(stats[F + j0 + 0] * invN - mu0 * mu0, 0.0f);
        float v1 = fmaxf(stats[F + j0 + 1] * invN - mu1 * mu1, 0.0f);
        float v2 = fmaxf(stats[F + j0 + 2] * invN - mu2 * mu2, 0.0f);
        float v3 = fmaxf(stats[F + j0 + 3] * invN - mu3 * mu3, 0.0f);
        sc.x = rsqrtf(v0 + BN_EPS) * g[j0 + 0];
        sc.y = rsqrtf(v1 + BN_EPS) * g[j0 + 1];
        sc.z = rsqrtf(v2 + BN_EPS) * g[j0 + 2];
        sc.w = rsqrtf(v3 + BN_EPS) * g[j0 + 3];
        sh.x = be[j0 + 0] - mu0 * sc.x;
        sh.y = be[j0 + 1] - mu1 * sc.y;
        sh.z = be[j0 + 2] - mu2 * sc.z;
        sh.w = be[j0 + 3] - mu3 * sc.w;
    }
    float4 yv = *(const float4*)(y + (size_t)i * F + j0);
    float4 v;
    v.x = fmaf(yv.x, sc.x, sh.x);
    v.y = fmaf(yv.y, sc.y, sh.y);
    v.z = fmaf(yv.z, sc.z, sh.z);
    v.w = fmaf(yv.w, sc.w, sh.w);
    if (POOL) {
        float* p = pool + (size_t)batch[i] * F + j0;
        atomicAdd(p + 0, v.x); atomicAdd(p + 1, v.y);
        atomicAdd(p + 2, v.z); atomicAdd(p + 3, v.w);
    } else {
        *(float4*)(z + (size_t)i * F + j0) = v;
        *(float4*)(agg + (size_t)i * F + j0) = v;
    }
}

// ---------------- FC head: [G,32] -> relu 128 -> relu 64 -> 10 ----------------
__global__ __launch_bounds__(128) void fc_kernel(const float* __restrict__ pool,
        const float* __restrict__ Wf1, const float* __restrict__ bf1,
        const float* __restrict__ Wf2, const float* __restrict__ bf2,
        const float* __restrict__ Wf3, const float* __restrict__ bf3,
        float* __restrict__ out) {
    __shared__ float zin[32];
    __shared__ float h1[128];
    __shared__ float h2[64];
    const int gidx = blockIdx.x;
    const int t = threadIdx.x;
    if (t < 32) zin[t] = pool[(size_t)gidx * 32 + t];
    __syncthreads();
    {
        float a = bf1[t];
        for (int k = 0; k < 32; k++) a = fmaf(zin[k], Wf1[k * 128 + t], a);
        h1[t] = fmaxf(a, 0.0f);
    }
    __syncthreads();
    if (t < 64) {
        float a = bf2[t];
        for (int k = 0; k < 128; k++) a = fmaf(h1[k], Wf2[k * 64 + t], a);
        h2[t] = fmaxf(a, 0.0f);
    }
    __syncthreads();
    if (t < 10) {
        float a = bf3[t];
        for (int k = 0; k < 64; k++) a = fmaf(h2[k], Wf3[k * 10 + t], a);
        out[(size_t)gidx * 10 + t] = a;
    }
}

extern "C" void kernel_launch(void* const* d_in, const int* in_sizes, int n_in,
                              void* d_out, int out_size, void* d_ws, size_t ws_size,
                              hipStream_t stream) {
    const float* x   = (const float*)d_in[0];
    const int*  ei   = (const int*)d_in[1];
    const int*  batch= (const int*)d_in[2];
    const float* W1a = (const float*)d_in[3];  const float* b1a = (const float*)d_in[4];
    const float* W1b = (const float*)d_in[5];  const float* b1b = (const float*)d_in[6];
    const float* g1  = (const float*)d_in[7];  const float* be1 = (const float*)d_in[8];
    const float* W2a = (const float*)d_in[9];  const float* b2a = (const float*)d_in[10];
    const float* W2b = (const float*)d_in[11]; const float* b2b = (const float*)d_in[12];
    const float* g2  = (const float*)d_in[13]; const float* be2 = (const float*)d_in[14];
    const float* W3a = (const float*)d_in[15]; const float* b3a = (const float*)d_in[16];
    const float* W3b = (const float*)d_in[17]; const float* b3b = (const float*)d_in[18];
    const float* g3  = (const float*)d_in[19]; const float* be3 = (const float*)d_in[20];
    const float* Wf1 = (const float*)d_in[21]; const float* bf1 = (const float*)d_in[22];
    const float* Wf2 = (const float*)d_in[23]; const float* bf2 = (const float*)d_in[24];
    const float* Wf3 = (const float*)d_in[25]; const float* bf3 = (const float*)d_in[26];

    const int N = in_sizes[2];
    const int E = in_sizes[1] / 2;
    const int G = out_size / 10;
    const int* src = ei;
    const int* dst = ei + E;

    // workspace layout (f32): B0[N*128] | B1[N*128] | pool[G*32] | stats 3*256
    float* B0   = (float*)d_ws;
    float* B1   = B0 + (size_t)N * 128;
    float* pool = B1 + (size_t)N * 128;
    float* st1  = pool + (size_t)G * 32;
    float* st2  = st1 + 256;
    float* st3  = st2 + 256;

    hipMemsetAsync(pool, 0, ((size_t)G * 32 + 768) * sizeof(float), stream);

    const float invN = 1.0f / (float)N;
    const int RB = 2048;   // row-blocks per gemm

    // ---- Layer 1: 64 -> 128 -> 128 ----
    copy_kernel<<<(N * 16 + 255) / 256, 256, 0, stream>>>(x, B0, N * 16);
    {
        long long t4 = (long long)E * 16;
        scatter_kernel<64><<<(unsigned)((t4 + 255) / 256), 256, 0, stream>>>(src, dst, x, B0, E);
    }
    gemm_kernel<64, 128, 128, false><<<RB, 256, 0, stream>>>(B0, W1a, b1a, B1, N, nullptr);
    gemm_kernel<128, 128, 64, true><<<RB * 2, 256, 0, stream>>>(B1, W1b, b1b, B0, N, st1);
    bn_kernel<128, false><<<(N * 32 + 255) / 256, 256, 0, stream>>>(B0, st1, g1, be1, B1, B0, nullptr, nullptr, N, invN);

    // ---- Layer 2: 128 -> 64 -> 64 ----
    {
        long long t4 = (long long)E * 32;
        scatter_kernel<128><<<(unsigned)((t4 + 255) / 256), 256, 0, stream>>>(src, dst, B1, B0, E);
    }
    gemm_kernel<128, 64, 64, false><<<RB, 256, 0, stream>>>(B0, W2a, b2a, B1, N, nullptr);
    gemm_kernel<64, 64, 64, true><<<RB, 256, 0, stream>>>(B1, W2b, b2b, B0, N, st2);
    bn_kernel<64, false><<<(N * 16 + 255) / 256, 256, 0, stream>>>(B0, st2, g2, be2, B1, B0, nullptr, nullptr, N, invN);

    // ---- Layer 3: 64 -> 32 -> 32 ----
    {
        long long t4 = (long long)E * 16;
        scatter_kernel<64><<<(unsigned)((t4 + 255) / 256), 256, 0, stream>>>(src, dst, B1, B0, E);
    }
    gemm_kernel<64, 32, 32, false><<<RB, 256, 0, stream>>>(B0, W3a, b3a, B1, N, nullptr);
    gemm_kernel<32, 32, 32, true><<<RB, 256, 0, stream>>>(B1, W3b, b3b, B0, N, st3);
    bn_kernel<32, true><<<(N * 8 + 255) / 256, 256, 0, stream>>>(B0, st3, g3, be3, nullptr, nullptr, batch, pool, N, invN);

    // ---- pooled MLP head ----
    fc_kernel<<<G, 128, 0, stream>>>(pool, Wf1, bf1, Wf2, bf2, Wf3, bf3, (float*)d_out);
}

// Round 3
// 1626.984 us; speedup vs baseline: 7.0971x; 7.0971x over previous
//
#include <hip/hip_runtime.h>

#define BN_EPS 1e-5f

// ================= CSR build =================
__global__ __launch_bounds__(256) void hist_kernel(const int* __restrict__ dst,
                                                   int* __restrict__ deg, int E) {
    int e = blockIdx.x * 256 + threadIdx.x;
    if (e < E) atomicAdd(&deg[dst[e]], 1);
}

// block-level inclusive scan of deg (N entries) into off[1..N]; block sums out
__global__ __launch_bounds__(1024) void scan_block(const int* __restrict__ deg,
        int* __restrict__ off, int* __restrict__ bsum, int N) {
    __shared__ int sh[1024];
    int g = blockIdx.x * 1024 + threadIdx.x;
    int v = (g < N) ? deg[g] : 0;
    sh[threadIdx.x] = v;
    __syncthreads();
    for (int d = 1; d < 1024; d <<= 1) {
        int t = (threadIdx.x >= d) ? sh[threadIdx.x - d] : 0;
        __syncthreads();
        sh[threadIdx.x] += t;
        __syncthreads();
    }
    if (g < N) off[g + 1] = sh[threadIdx.x];
    if (threadIdx.x == 1023) bsum[blockIdx.x] = sh[1023];
    if (g == 0) off[0] = 0;
}

// single-block exclusive scan of block sums (nb <= 128)
__global__ __launch_bounds__(128) void scan_bsum(int* __restrict__ bsum, int nb) {
    __shared__ int sh[128];
    int v = (threadIdx.x < nb) ? bsum[threadIdx.x] : 0;
    sh[threadIdx.x] = v;
    __syncthreads();
    for (int d = 1; d < 128; d <<= 1) {
        int t = (threadIdx.x >= d) ? sh[threadIdx.x - d] : 0;
        __syncthreads();
        sh[threadIdx.x] += t;
        __syncthreads();
    }
    if (threadIdx.x < nb) bsum[threadIdx.x] = sh[threadIdx.x] - v;  // exclusive
}

// add scanned block sums; also initialize fill cursors cur[] = off[]
__global__ __launch_bounds__(1024) void scan_finish(int* __restrict__ off,
        int* __restrict__ cur, const int* __restrict__ bsum, int N) {
    int g = blockIdx.x * 1024 + threadIdx.x;
    if (g < N) {
        int v = off[g + 1] + bsum[blockIdx.x];
        off[g + 1] = v;
        cur[g + 1] = v;
    }
    if (g == 0) cur[0] = 0;
}

__global__ __launch_bounds__(256) void fill_kernel(const int* __restrict__ src,
        const int* __restrict__ dst, int* __restrict__ cur,
        int* __restrict__ elist, int E) {
    int e = blockIdx.x * 256 + threadIdx.x;
    if (e < E) {
        int slot = atomicAdd(&cur[dst[e]], 1);
        elist[slot] = src[e];
    }
}

// ================= gather: agg[i] = in[i] + sum_{s in nbrs(i)} in[s] =================
// F lanes per node; one block = 256 threads = 256/F nodes
template<int F>
__global__ __launch_bounds__(256) void gather_kernel(const int* __restrict__ off,
        const int* __restrict__ elist, const float* __restrict__ in,
        float* __restrict__ agg, int N) {
    int t = blockIdx.x * 256 + threadIdx.x;
    int i = t / F;
    int j = t & (F - 1);
    if (i >= N) return;
    float acc = in[(size_t)i * F + j];
    int k = off[i], e = off[i + 1];
    for (; k + 4 <= e; k += 4) {
        int n0 = elist[k], n1 = elist[k + 1], n2 = elist[k + 2], n3 = elist[k + 3];
        float a0 = in[(size_t)n0 * F + j];
        float a1 = in[(size_t)n1 * F + j];
        float a2 = in[(size_t)n2 * F + j];
        float a3 = in[(size_t)n3 * F + j];
        acc += (a0 + a1) + (a2 + a3);
    }
    for (; k < e; k++) acc += in[(size_t)elist[k] * F + j];
    agg[(size_t)i * F + j] = acc;
}

// ================= GEMM: Out = relu(A @ W + b), optional column stats =================
template<int FIN, int FOUT, int CT, bool STATS>
__global__ __launch_bounds__(256) void gemm_kernel(const float* __restrict__ A,
        const float* __restrict__ W, const float* __restrict__ bias,
        float* __restrict__ Out, int N, float* __restrict__ stats) {
    constexpr int NCB = FOUT / CT;
    __shared__ float Ws[FIN * CT];
    __shared__ float Bs[CT];
    __shared__ float Ss[STATS ? 2 * CT : 1];
    const int cb = blockIdx.x % NCB;
    const int rb = blockIdx.x / NCB;
    const int c0 = cb * CT;
    for (int i = threadIdx.x; i < FIN * CT; i += 256) {
        int k = i / CT, jj = i & (CT - 1);
        Ws[i] = W[(size_t)k * FOUT + c0 + jj];
    }
    if (threadIdx.x < CT) Bs[threadIdx.x] = bias[c0 + threadIdx.x];
    if (STATS) for (int i = threadIdx.x; i < 2 * CT; i += 256) Ss[i] = 0.0f;
    __syncthreads();

    constexpr int GROUPS = 256 / CT;
    constexpr int RPI = GROUPS * 4;
    const int j = threadIdx.x & (CT - 1);
    const int grp = threadIdx.x / CT;
    const float bj = Bs[j];
    const int RB = gridDim.x / NCB;
    float ls = 0.0f, ls2 = 0.0f;

    for (int base = (rb * GROUPS + grp) * 4; base < N; base += RB * RPI) {
        const float* a = A + (size_t)base * FIN;
        if (base + 4 <= N) {
            float acc0 = bj, acc1 = bj, acc2 = bj, acc3 = bj;
            for (int k = 0; k < FIN; k++) {
                float w = Ws[k * CT + j];
                acc0 = fmaf(a[k],           w, acc0);
                acc1 = fmaf(a[FIN + k],     w, acc1);
                acc2 = fmaf(a[2 * FIN + k], w, acc2);
                acc3 = fmaf(a[3 * FIN + k], w, acc3);
            }
            acc0 = fmaxf(acc0, 0.0f); acc1 = fmaxf(acc1, 0.0f);
            acc2 = fmaxf(acc2, 0.0f); acc3 = fmaxf(acc3, 0.0f);
            float* o = Out + (size_t)base * FOUT + c0 + j;
            o[0] = acc0; o[FOUT] = acc1; o[2 * FOUT] = acc2; o[3 * FOUT] = acc3;
            if (STATS) {
                ls  += acc0 + acc1 + acc2 + acc3;
                ls2 += acc0 * acc0 + acc1 * acc1 + acc2 * acc2 + acc3 * acc3;
            }
        } else {
            for (int r = 0; r < 4 && base + r < N; r++) {
                float acc = bj;
                for (int k = 0; k < FIN; k++)
                    acc = fmaf(a[(size_t)r * FIN + k], Ws[k * CT + j], acc);
                acc = fmaxf(acc, 0.0f);
                Out[(size_t)(base + r) * FOUT + c0 + j] = acc;
                if (STATS) { ls += acc; ls2 += acc * acc; }
            }
        }
    }
    if (STATS) {
        atomicAdd(&Ss[j], ls);
        atomicAdd(&Ss[CT + j], ls2);
        __syncthreads();
        for (int i = threadIdx.x; i < CT; i += 256) {
            atomicAdd(&stats[c0 + i], Ss[i]);
            atomicAdd(&stats[FOUT + c0 + i], Ss[CT + i]);
        }
    }
}

// ================= BN apply =================
// !POOL: z[i] = bn(y[i]).  POOL: atomicAdd bn(y[i]) into pool[batch[row]].
template<int F, bool POOL>
__global__ __launch_bounds__(256) void bn_kernel(const float* __restrict__ y,
        const float* __restrict__ stats, const float* __restrict__ g,
        const float* __restrict__ be, float* __restrict__ z,
        const int* __restrict__ batch, float* __restrict__ pool, int N, float invN) {
    constexpr int QF = F / 4;
    int idx = blockIdx.x * 256 + threadIdx.x;
    if (idx >= N * QF) return;
    int q = idx & (QF - 1);
    int i = idx / QF;
    int j0 = q * 4;
    float4 sc, sh;
    {
        float mu0 = stats[j0 + 0] * invN, mu1 = stats[j0 + 1] * invN;
        float mu2 = stats[j0 + 2] * invN, mu3 = stats[j0 + 3] * invN;
        float v0 = fmaxf(stats[F + j0 + 0] * invN - mu0 * mu0, 0.0f);
        float v1 = fmaxf(stats[F + j0 + 1] * invN - mu1 * mu1, 0.0f);
        float v2 = fmaxf(stats[F + j0 + 2] * invN - mu2 * mu2, 0.0f);
        float v3 = fmaxf(stats[F + j0 + 3] * invN - mu3 * mu3, 0.0f);
        sc.x = rsqrtf(v0 + BN_EPS) * g[j0 + 0];
        sc.y = rsqrtf(v1 + BN_EPS) * g[j0 + 1];
        sc.z = rsqrtf(v2 + BN_EPS) * g[j0 + 2];
        sc.w = rsqrtf(v3 + BN_EPS) * g[j0 + 3];
        sh.x = be[j0 + 0] - mu0 * sc.x;
        sh.y = be[j0 + 1] - mu1 * sc.y;
        sh.z = be[j0 + 2] - mu2 * sc.z;
        sh.w = be[j0 + 3] - mu3 * sc.w;
    }
    float4 yv = *(const float4*)(y + (size_t)i * F + j0);
    float4 v;
    v.x = fmaf(yv.x, sc.x, sh.x);
    v.y = fmaf(yv.y, sc.y, sh.y);
    v.z = fmaf(yv.z, sc.z, sh.z);
    v.w = fmaf(yv.w, sc.w, sh.w);
    if (POOL) {
        float* p = pool + (size_t)batch[i] * F + j0;
        atomicAdd(p + 0, v.x); atomicAdd(p + 1, v.y);
        atomicAdd(p + 2, v.z); atomicAdd(p + 3, v.w);
    } else {
        *(float4*)(z + (size_t)i * F + j0) = v;
    }
}

// ================= FC head: [G,32] -> relu 128 -> relu 64 -> 10 =================
__global__ __launch_bounds__(128) void fc_kernel(const float* __restrict__ pool,
        const float* __restrict__ Wf1, const float* __restrict__ bf1,
        const float* __restrict__ Wf2, const float* __restrict__ bf2,
        const float* __restrict__ Wf3, const float* __restrict__ bf3,
        float* __restrict__ out) {
    __shared__ float zin[32];
    __shared__ float h1[128];
    __shared__ float h2[64];
    const int gidx = blockIdx.x;
    const int t = threadIdx.x;
    if (t < 32) zin[t] = pool[(size_t)gidx * 32 + t];
    __syncthreads();
    {
        float a = bf1[t];
        for (int k = 0; k < 32; k++) a = fmaf(zin[k], Wf1[k * 128 + t], a);
        h1[t] = fmaxf(a, 0.0f);
    }
    __syncthreads();
    if (t < 64) {
        float a = bf2[t];
        for (int k = 0; k < 128; k++) a = fmaf(h1[k], Wf2[k * 64 + t], a);
        h2[t] = fmaxf(a, 0.0f);
    }
    __syncthreads();
    if (t < 10) {
        float a = bf3[t];
        for (int k = 0; k < 64; k++) a = fmaf(h2[k], Wf3[k * 10 + t], a);
        out[(size_t)gidx * 10 + t] = a;
    }
}

extern "C" void kernel_launch(void* const* d_in, const int* in_sizes, int n_in,
                              void* d_out, int out_size, void* d_ws, size_t ws_size,
                              hipStream_t stream) {
    const float* x   = (const float*)d_in[0];
    const int*  ei   = (const int*)d_in[1];
    const int*  batch= (const int*)d_in[2];
    const float* W1a = (const float*)d_in[3];  const float* b1a = (const float*)d_in[4];
    const float* W1b = (const float*)d_in[5];  const float* b1b = (const float*)d_in[6];
    const float* g1  = (const float*)d_in[7];  const float* be1 = (const float*)d_in[8];
    const float* W2a = (const float*)d_in[9];  const float* b2a = (const float*)d_in[10];
    const float* W2b = (const float*)d_in[11]; const float* b2b = (const float*)d_in[12];
    const float* g2  = (const float*)d_in[13]; const float* be2 = (const float*)d_in[14];
    const float* W3a = (const float*)d_in[15]; const float* b3a = (const float*)d_in[16];
    const float* W3b = (const float*)d_in[17]; const float* b3b = (const float*)d_in[18];
    const float* g3  = (const float*)d_in[19]; const float* be3 = (const float*)d_in[20];
    const float* Wf1 = (const float*)d_in[21]; const float* bf1 = (const float*)d_in[22];
    const float* Wf2 = (const float*)d_in[23]; const float* bf2 = (const float*)d_in[24];
    const float* Wf3 = (const float*)d_in[25]; const float* bf3 = (const float*)d_in[26];

    const int N = in_sizes[2];
    const int E = in_sizes[1] / 2;
    const int G = out_size / 10;
    const int* src = ei;
    const int* dst = ei + E;

    // ws layout (f32): B0[N*128] | B1[N*128] | pool[G*32] | stats 3*256 |
    //                  (int) off[N+1] | cur[N+1] | bsum[128] | elist[E]
    float* B0   = (float*)d_ws;
    float* B1   = B0 + (size_t)N * 128;
    float* pool = B1 + (size_t)N * 128;
    float* st1  = pool + (size_t)G * 32;
    float* st2  = st1 + 256;
    float* st3  = st2 + 256;
    int* off    = (int*)(st3 + 256);
    int* cur    = off + (N + 1);
    int* bsum   = cur + (N + 1);
    int* elist  = bsum + 128;

    hipMemsetAsync(pool, 0, ((size_t)G * 32 + 768) * sizeof(float), stream);
    hipMemsetAsync(cur, 0, (size_t)N * sizeof(int), stream);  // deg accumulator

    const float invN = 1.0f / (float)N;
    const int RB = 2048;
    const int NB = (N + 1023) / 1024;

    // ---- CSR build (dst-keyed; reused by all 3 layers) ----
    hist_kernel<<<(E + 255) / 256, 256, 0, stream>>>(dst, cur, E);
    scan_block<<<NB, 1024, 0, stream>>>(cur, off, bsum, N);
    scan_bsum<<<1, 128, 0, stream>>>(bsum, NB);
    scan_finish<<<NB, 1024, 0, stream>>>(off, cur, bsum, N);
    fill_kernel<<<(E + 255) / 256, 256, 0, stream>>>(src, dst, cur, elist, E);

    // ---- Layer 1: 64 -> 128 -> 128 ----
    gather_kernel<64><<<(N * 64 + 255) / 256, 256, 0, stream>>>(off, elist, x, B0, N);
    gemm_kernel<64, 128, 128, false><<<RB, 256, 0, stream>>>(B0, W1a, b1a, B1, N, nullptr);
    gemm_kernel<128, 128, 64, true><<<RB * 2, 256, 0, stream>>>(B1, W1b, b1b, B0, N, st1);
    bn_kernel<128, false><<<(N * 32 + 255) / 256, 256, 0, stream>>>(B0, st1, g1, be1, B1, nullptr, nullptr, N, invN);

    // ---- Layer 2: 128 -> 64 -> 64 ----
    gather_kernel<128><<<(N * 128 + 255) / 256, 256, 0, stream>>>(off, elist, B1, B0, N);
    gemm_kernel<128, 64, 64, false><<<RB, 256, 0, stream>>>(B0, W2a, b2a, B1, N, nullptr);
    gemm_kernel<64, 64, 64, true><<<RB, 256, 0, stream>>>(B1, W2b, b2b, B0, N, st2);
    bn_kernel<64, false><<<(N * 16 + 255) / 256, 256, 0, stream>>>(B0, st2, g2, be2, B1, nullptr, nullptr, N, invN);

    // ---- Layer 3: 64 -> 32 -> 32 ----
    gather_kernel<64><<<(N * 64 + 255) / 256, 256, 0, stream>>>(off, elist, B1, B0, N);
    gemm_kernel<64, 32, 32, false><<<RB, 256, 0, stream>>>(B0, W3a, b3a, B1, N, nullptr);
    gemm_kernel<32, 32, 32, true><<<RB, 256, 0, stream>>>(B1, W3b, b3b, B0, N, st3);
    bn_kernel<32, true><<<(N * 8 + 255) / 256, 256, 0, stream>>>(B0, st3, g3, be3, nullptr, batch, pool, N, invN);

    // ---- pooled MLP head ----
    fc_kernel<<<G, 128, 0, stream>>>(pool, Wf1, bf1, Wf2, bf2, Wf3, bf3, (float*)d_out);
}

// Round 4
// 1315.481 us; speedup vs baseline: 8.7776x; 1.2368x over previous
//
#include <hip/hip_runtime.h>

#define BN_EPS 1e-5f

typedef unsigned short ushortt;

__device__ inline float bf2f(ushortt u) {
    return __uint_as_float(((unsigned)u) << 16);
}
__device__ inline ushortt f2bf(float f) {
    unsigned u = __float_as_uint(f);
    return (ushortt)((u + 0x7FFFu + ((u >> 16) & 1u)) >> 16);  // RNE
}

// ================= x -> bf16 convert =================
__global__ __launch_bounds__(256) void conv_kernel(const float4* __restrict__ in,
        ushort4* __restrict__ out, int n4) {
    int i = blockIdx.x * 256 + threadIdx.x;
    if (i < n4) {
        float4 v = in[i];
        ushort4 o;
        o.x = f2bf(v.x); o.y = f2bf(v.y); o.z = f2bf(v.z); o.w = f2bf(v.w);
        out[i] = o;
    }
}

// ================= CSR build =================
// deg histogram + per-edge rank (contiguous write)
__global__ __launch_bounds__(256) void hist_kernel(const int* __restrict__ dst,
        int* __restrict__ deg, int* __restrict__ rank, int E) {
    int e = blockIdx.x * 256 + threadIdx.x;
    if (e < E) rank[e] = atomicAdd(&deg[dst[e]], 1);
}

__global__ __launch_bounds__(1024) void scan_block(const int* __restrict__ deg,
        int* __restrict__ off, int* __restrict__ bsum, int N) {
    __shared__ int sh[1024];
    int g = blockIdx.x * 1024 + threadIdx.x;
    int v = (g < N) ? deg[g] : 0;
    sh[threadIdx.x] = v;
    __syncthreads();
    for (int d = 1; d < 1024; d <<= 1) {
        int t = (threadIdx.x >= d) ? sh[threadIdx.x - d] : 0;
        __syncthreads();
        sh[threadIdx.x] += t;
        __syncthreads();
    }
    if (g < N) off[g + 1] = sh[threadIdx.x];
    if (threadIdx.x == 1023) bsum[blockIdx.x] = sh[1023];
    if (g == 0) off[0] = 0;
}

__global__ __launch_bounds__(128) void scan_bsum(int* __restrict__ bsum, int nb) {
    __shared__ int sh[128];
    int v = (threadIdx.x < nb) ? bsum[threadIdx.x] : 0;
    sh[threadIdx.x] = v;
    __syncthreads();
    for (int d = 1; d < 128; d <<= 1) {
        int t = (threadIdx.x >= d) ? sh[threadIdx.x - d] : 0;
        __syncthreads();
        sh[threadIdx.x] += t;
        __syncthreads();
    }
    if (threadIdx.x < nb) bsum[threadIdx.x] = sh[threadIdx.x] - v;  // exclusive
}

__global__ __launch_bounds__(1024) void scan_finish(int* __restrict__ off,
        const int* __restrict__ bsum, int N) {
    int g = blockIdx.x * 1024 + threadIdx.x;
    if (g < N) off[g + 1] += bsum[blockIdx.x];
}

// atomic-free fill: slot = off[dst] + rank
__global__ __launch_bounds__(256) void fill_kernel(const int* __restrict__ src,
        const int* __restrict__ dst, const int* __restrict__ rank,
        const int* __restrict__ off, int* __restrict__ elist, int E) {
    int e = blockIdx.x * 256 + threadIdx.x;
    if (e < E) elist[off[dst[e]] + rank[e]] = src[e];
}

// ================= gather (+ optional fused BN of the producing layer) ========
// BN==false: agg[i] = in[i] + sum_{s} in[s]
// BN==true : agg[i] = sc * (in[i] + sum in[s]) + (deg+1) * sh    (per column)
template<int F, bool BN>
__global__ __launch_bounds__(256) void gather_kernel(const int* __restrict__ off,
        const int* __restrict__ elist, const ushortt* __restrict__ in,
        float* __restrict__ agg, const float* __restrict__ stats,
        const float* __restrict__ gw, const float* __restrict__ bw,
        int N, float invN) {
    int t = blockIdx.x * 256 + threadIdx.x;
    int i = t / F;
    int j = t & (F - 1);
    if (i >= N) return;
    float sc = 1.0f, sh = 0.0f;
    if (BN) {
        float mu = stats[j] * invN;
        float var = fmaxf(stats[F + j] * invN - mu * mu, 0.0f);
        sc = rsqrtf(var + BN_EPS) * gw[j];
        sh = bw[j] - mu * sc;
    }
    int k = off[i], e = off[i + 1];
    float cnt = (float)(e - k + 1);
    float acc = bf2f(in[(size_t)i * F + j]);
    for (; k + 4 <= e; k += 4) {
        int n0 = elist[k], n1 = elist[k + 1], n2 = elist[k + 2], n3 = elist[k + 3];
        float a0 = bf2f(in[(size_t)n0 * F + j]);
        float a1 = bf2f(in[(size_t)n1 * F + j]);
        float a2 = bf2f(in[(size_t)n2 * F + j]);
        float a3 = bf2f(in[(size_t)n3 * F + j]);
        acc += (a0 + a1) + (a2 + a3);
    }
    for (; k < e; k++) acc += bf2f(in[(size_t)elist[k] * F + j]);
    if (BN) acc = fmaf(acc, sc, cnt * sh);
    agg[(size_t)i * F + j] = acc;
}

// ================= GEMM: Out = relu(A @ W + b), col stats, f32/bf16 out =======
template<int FIN, int FOUT, int CT, bool STATS, bool OUTBF>
__global__ __launch_bounds__(256) void gemm_kernel(const float* __restrict__ A,
        const float* __restrict__ W, const float* __restrict__ bias,
        void* __restrict__ OutV, int N, float* __restrict__ stats) {
    typedef typename std::conditional<OUTBF, ushortt, float>::type OutT;
    OutT* Out = (OutT*)OutV;
    constexpr int NCB = FOUT / CT;
    __shared__ float Ws[FIN * CT];
    __shared__ float Bs[CT];
    __shared__ float Ss[STATS ? 2 * CT : 1];
    const int cb = blockIdx.x % NCB;
    const int rb = blockIdx.x / NCB;
    const int c0 = cb * CT;
    for (int i = threadIdx.x; i < FIN * CT; i += 256) {
        int k = i / CT, jj = i & (CT - 1);
        Ws[i] = W[(size_t)k * FOUT + c0 + jj];
    }
    if (threadIdx.x < CT) Bs[threadIdx.x] = bias[c0 + threadIdx.x];
    if (STATS) for (int i = threadIdx.x; i < 2 * CT; i += 256) Ss[i] = 0.0f;
    __syncthreads();

    constexpr int GROUPS = 256 / CT;
    constexpr int RPI = GROUPS * 4;
    const int j = threadIdx.x & (CT - 1);
    const int grp = threadIdx.x / CT;
    const float bj = Bs[j];
    const int RB = gridDim.x / NCB;
    float ls = 0.0f, ls2 = 0.0f;

    for (int base = (rb * GROUPS + grp) * 4; base < N; base += RB * RPI) {
        const float* a = A + (size_t)base * FIN;
        if (base + 4 <= N) {
            float acc0 = bj, acc1 = bj, acc2 = bj, acc3 = bj;
            for (int k = 0; k < FIN; k++) {
                float w = Ws[k * CT + j];
                acc0 = fmaf(a[k],           w, acc0);
                acc1 = fmaf(a[FIN + k],     w, acc1);
                acc2 = fmaf(a[2 * FIN + k], w, acc2);
                acc3 = fmaf(a[3 * FIN + k], w, acc3);
            }
            acc0 = fmaxf(acc0, 0.0f); acc1 = fmaxf(acc1, 0.0f);
            acc2 = fmaxf(acc2, 0.0f); acc3 = fmaxf(acc3, 0.0f);
            OutT* o = Out + (size_t)base * FOUT + c0 + j;
            if (OUTBF) {
                o[0] = (OutT)f2bf(acc0); o[FOUT] = (OutT)f2bf(acc1);
                o[2 * FOUT] = (OutT)f2bf(acc2); o[3 * FOUT] = (OutT)f2bf(acc3);
            } else {
                o[0] = (OutT)acc0; o[FOUT] = (OutT)acc1;
                o[2 * FOUT] = (OutT)acc2; o[3 * FOUT] = (OutT)acc3;
            }
            if (STATS) {
                ls  += acc0 + acc1 + acc2 + acc3;
                ls2 += acc0 * acc0 + acc1 * acc1 + acc2 * acc2 + acc3 * acc3;
            }
        } else {
            for (int r = 0; r < 4 && base + r < N; r++) {
                float acc = bj;
                for (int k = 0; k < FIN; k++)
                    acc = fmaf(a[(size_t)r * FIN + k], Ws[k * CT + j], acc);
                acc = fmaxf(acc, 0.0f);
                if (OUTBF) Out[(size_t)(base + r) * FOUT + c0 + j] = (OutT)f2bf(acc);
                else       Out[(size_t)(base + r) * FOUT + c0 + j] = (OutT)acc;
                if (STATS) { ls += acc; ls2 += acc * acc; }
            }
        }
    }
    if (STATS) {
        atomicAdd(&Ss[j], ls);
        atomicAdd(&Ss[CT + j], ls2);
        __syncthreads();
        for (int i = threadIdx.x; i < CT; i += 256) {
            atomicAdd(&stats[c0 + i], Ss[i]);
            atomicAdd(&stats[FOUT + c0 + i], Ss[CT + i]);
        }
    }
}

// ================= layer-3 BN + segmented pool (batch is sorted) =============
__global__ __launch_bounds__(256) void bn_pool_kernel(const float* __restrict__ y,
        const float* __restrict__ stats, const float* __restrict__ gw,
        const float* __restrict__ bw, const int* __restrict__ batch,
        float* __restrict__ pool, int N, float invN) {
    constexpr int F = 32, CH = 64;
    int q = threadIdx.x >> 5;
    int j = threadIdx.x & 31;
    int r0 = (blockIdx.x * 8 + q) * CH;
    if (r0 >= N) return;
    int r1 = min(r0 + CH, N);
    float mu = stats[j] * invN;
    float var = fmaxf(stats[F + j] * invN - mu * mu, 0.0f);
    float sc = rsqrtf(var + BN_EPS) * gw[j];
    float sh = bw[j] - mu * sc;
    int curg = batch[r0];
    float acc = 0.0f;
    for (int r = r0; r < r1; r++) {
        int g = batch[r];
        if (g != curg) {
            atomicAdd(pool + (size_t)curg * 32 + j, acc);
            acc = 0.0f;
            curg = g;
        }
        acc = fmaf(y[(size_t)r * 32 + j], sc, sh + acc);
    }
    atomicAdd(pool + (size_t)curg * 32 + j, acc);
}

// ================= FC head =================
__global__ __launch_bounds__(128) void fc_kernel(const float* __restrict__ pool,
        const float* __restrict__ Wf1, const float* __restrict__ bf1,
        const float* __restrict__ Wf2, const float* __restrict__ bf2,
        const float* __restrict__ Wf3, const float* __restrict__ bf3,
        float* __restrict__ out) {
    __shared__ float zin[32];
    __shared__ float h1[128];
    __shared__ float h2[64];
    const int gidx = blockIdx.x;
    const int t = threadIdx.x;
    if (t < 32) zin[t] = pool[(size_t)gidx * 32 + t];
    __syncthreads();
    {
        float a = bf1[t];
        for (int k = 0; k < 32; k++) a = fmaf(zin[k], Wf1[k * 128 + t], a);
        h1[t] = fmaxf(a, 0.0f);
    }
    __syncthreads();
    if (t < 64) {
        float a = bf2[t];
        for (int k = 0; k < 128; k++) a = fmaf(h1[k], Wf2[k * 64 + t], a);
        h2[t] = fmaxf(a, 0.0f);
    }
    __syncthreads();
    if (t < 10) {
        float a = bf3[t];
        for (int k = 0; k < 64; k++) a = fmaf(h2[k], Wf3[k * 10 + t], a);
        out[(size_t)gidx * 10 + t] = a;
    }
}

extern "C" void kernel_launch(void* const* d_in, const int* in_sizes, int n_in,
                              void* d_out, int out_size, void* d_ws, size_t ws_size,
                              hipStream_t stream) {
    const float* x   = (const float*)d_in[0];
    const int*  ei   = (const int*)d_in[1];
    const int*  batch= (const int*)d_in[2];
    const float* W1a = (const float*)d_in[3];  const float* b1a = (const float*)d_in[4];
    const float* W1b = (const float*)d_in[5];  const float* b1b = (const float*)d_in[6];
    const float* g1  = (const float*)d_in[7];  const float* be1 = (const float*)d_in[8];
    const float* W2a = (const float*)d_in[9];  const float* b2a = (const float*)d_in[10];
    const float* W2b = (const float*)d_in[11]; const float* b2b = (const float*)d_in[12];
    const float* g2  = (const float*)d_in[13]; const float* be2 = (const float*)d_in[14];
    const float* W3a = (const float*)d_in[15]; const float* b3a = (const float*)d_in[16];
    const float* W3b = (const float*)d_in[17]; const float* b3b = (const float*)d_in[18];
    const float* g3  = (const float*)d_in[19]; const float* be3 = (const float*)d_in[20];
    const float* Wf1 = (const float*)d_in[21]; const float* bf1 = (const float*)d_in[22];
    const float* Wf2 = (const float*)d_in[23]; const float* bf2 = (const float*)d_in[24];
    const float* Wf3 = (const float*)d_in[25]; const float* bf3 = (const float*)d_in[26];

    const int N = in_sizes[2];
    const int E = in_sizes[1] / 2;
    const int G = out_size / 10;
    const int* src = ei;
    const int* dst = ei + E;

    // ---- dedicated ws layout (f32 units) ----
    float* B0   = (float*)d_ws;              // N*128 f32
    float* B1   = B0 + (size_t)N * 128;      // N*128 f32
    float* pool = B1 + (size_t)N * 128;      // G*32
    float* st1  = pool + (size_t)G * 32;     // 256 each
    float* st2  = st1 + 256;
    float* st3  = st2 + 256;
    int* off    = (int*)(st3 + 256);         // N+1
    int* bsum   = off + (N + 1);             // 128
    int* elist  = bsum + 128;                // E

    // ---- aliases into dead regions (stream-order safe) ----
    int* deg      = (int*)B0;                // N ints     (CSR phase only)
    int* rank     = (int*)B0 + N;            // E ints     (CSR phase only)
    ushortt* xbf  = (ushortt*)B1;            // N*64 bf16  (until L1 gemm-a writes B1)
    ushortt* Y1   = (ushortt*)B0;            // N*128 bf16 (L1 gemm-b out)
    float*   H2   = B0 + (size_t)N * 64;     // N*64 f32   (L2 gemm-a out)
    ushortt* Y2   = (ushortt*)B0;            // N*64 bf16  (L2 gemm-b out)
    float*   H3   = B0 + (size_t)N * 64;     // N*32 f32   (L3 gemm-a out)
    float*   Y3   = B1;                      // N*32 f32   (L3 gemm-b out)

    hipMemsetAsync(pool, 0, ((size_t)G * 32 + 768) * sizeof(float), stream);
    hipMemsetAsync(deg, 0, (size_t)N * sizeof(int), stream);

    const float invN = 1.0f / (float)N;
    const int RB = 2048;
    const int NB = (N + 1023) / 1024;

    // ---- x -> bf16 ----
    conv_kernel<<<(N * 16 + 255) / 256, 256, 0, stream>>>((const float4*)x, (ushort4*)xbf, N * 16);

    // ---- CSR build ----
    hist_kernel<<<(E + 255) / 256, 256, 0, stream>>>(dst, deg, rank, E);
    scan_block<<<NB, 1024, 0, stream>>>(deg, off, bsum, N);
    scan_bsum<<<1, 128, 0, stream>>>(bsum, NB);
    scan_finish<<<NB, 1024, 0, stream>>>(off, bsum, N);
    fill_kernel<<<(E + 255) / 256, 256, 0, stream>>>(src, dst, rank, off, elist, E);

    // ---- Layer 1: gather(x) -> 128 -> 128(stats, bf16) ----
    gather_kernel<64, false><<<(N * 64 + 255) / 256, 256, 0, stream>>>(off, elist, xbf, B0, nullptr, nullptr, nullptr, N, invN);
    gemm_kernel<64, 128, 128, false, false><<<RB, 256, 0, stream>>>(B0, W1a, b1a, B1, N, nullptr);
    gemm_kernel<128, 128, 64, true, true><<<RB * 2, 256, 0, stream>>>(B1, W1b, b1b, Y1, N, st1);

    // ---- Layer 2: gather+BN1(Y1) -> 64 -> 64(stats, bf16) ----
    gather_kernel<128, true><<<(N * 128 + 255) / 256, 256, 0, stream>>>(off, elist, Y1, B1, st1, g1, be1, N, invN);
    gemm_kernel<128, 64, 64, false, false><<<RB, 256, 0, stream>>>(B1, W2a, b2a, H2, N, nullptr);
    gemm_kernel<64, 64, 64, true, true><<<RB, 256, 0, stream>>>(H2, W2b, b2b, Y2, N, st2);

    // ---- Layer 3: gather+BN2(Y2) -> 32 -> 32(stats, f32) ----
    gather_kernel<64, true><<<(N * 64 + 255) / 256, 256, 0, stream>>>(off, elist, Y2, B1, st2, g2, be2, N, invN);
    gemm_kernel<64, 32, 32, false, false><<<RB, 256, 0, stream>>>(B1, W3a, b3a, H3, N, nullptr);
    gemm_kernel<32, 32, 32, true, false><<<RB, 256, 0, stream>>>(H3, W3b, b3b, Y3, N, st3);

    // ---- BN3 + segmented pool ----
    bn_pool_kernel<<<(N + 511) / 512, 256, 0, stream>>>(Y3, st3, g3, be3, batch, pool, N, invN);

    // ---- pooled MLP head ----
    fc_kernel<<<G, 128, 0, stream>>>(pool, Wf1, bf1, Wf2, bf2, Wf3, bf3, (float*)d_out);
}

// Round 5
// 851.572 us; speedup vs baseline: 13.5594x; 1.5448x over previous
//
#include <hip/hip_runtime.h>

#define BN_EPS 1e-5f

typedef _Float16 f16;
typedef _Float16 f16x8 __attribute__((ext_vector_type(8)));
typedef _Float16 f16x4 __attribute__((ext_vector_type(4)));
typedef float f32x4 __attribute__((ext_vector_type(4)));

// ================= x -> f16 convert =================
__global__ __launch_bounds__(256) void conv_kernel(const float4* __restrict__ in,
        f16x4* __restrict__ out, int n4) {
    int i = blockIdx.x * 256 + threadIdx.x;
    if (i < n4) {
        float4 v = in[i];
        f16x4 o;
        o.x = (f16)v.x; o.y = (f16)v.y; o.z = (f16)v.z; o.w = (f16)v.w;
        out[i] = o;
    }
}

// ================= CSR build =================
__global__ __launch_bounds__(256) void hist_kernel(const int* __restrict__ dst,
        int* __restrict__ deg, int* __restrict__ rank, int E) {
    int e = blockIdx.x * 256 + threadIdx.x;
    if (e < E) rank[e] = atomicAdd(&deg[dst[e]], 1);
}

__global__ __launch_bounds__(1024) void scan_block(const int* __restrict__ deg,
        int* __restrict__ off, int* __restrict__ bsum, int N) {
    __shared__ int sh[1024];
    int g = blockIdx.x * 1024 + threadIdx.x;
    int v = (g < N) ? deg[g] : 0;
    sh[threadIdx.x] = v;
    __syncthreads();
    for (int d = 1; d < 1024; d <<= 1) {
        int t = (threadIdx.x >= d) ? sh[threadIdx.x - d] : 0;
        __syncthreads();
        sh[threadIdx.x] += t;
        __syncthreads();
    }
    if (g < N) off[g + 1] = sh[threadIdx.x];
    if (threadIdx.x == 1023) bsum[blockIdx.x] = sh[1023];
    if (g == 0) off[0] = 0;
}

__global__ __launch_bounds__(128) void scan_bsum(int* __restrict__ bsum, int nb) {
    __shared__ int sh[128];
    int v = (threadIdx.x < nb) ? bsum[threadIdx.x] : 0;
    sh[threadIdx.x] = v;
    __syncthreads();
    for (int d = 1; d < 128; d <<= 1) {
        int t = (threadIdx.x >= d) ? sh[threadIdx.x - d] : 0;
        __syncthreads();
        sh[threadIdx.x] += t;
        __syncthreads();
    }
    if (threadIdx.x < nb) bsum[threadIdx.x] = sh[threadIdx.x] - v;  // exclusive
}

__global__ __launch_bounds__(1024) void scan_finish(int* __restrict__ off,
        const int* __restrict__ bsum, int N) {
    int g = blockIdx.x * 1024 + threadIdx.x;
    if (g < N) off[g + 1] += bsum[blockIdx.x];
}

__global__ __launch_bounds__(256) void fill_kernel(const int* __restrict__ src,
        const int* __restrict__ dst, const int* __restrict__ rank,
        const int* __restrict__ off, int* __restrict__ elist, int E) {
    int e = blockIdx.x * 256 + threadIdx.x;
    if (e < E) elist[off[dst[e]] + rank[e]] = src[e];
}

// ================= gather (+ optional fused BN of producing layer) ============
// BN==false: agg[i] = in[i] + sum_{s} in[s]
// BN==true : agg[i] = sc * (in[i] + sum in[s]) + (deg+1) * sh
template<int F, bool BN>
__global__ __launch_bounds__(256) void gather_kernel(const int* __restrict__ off,
        const int* __restrict__ elist, const f16* __restrict__ in,
        f16* __restrict__ agg, const float* __restrict__ stats,
        const float* __restrict__ gw, const float* __restrict__ bw,
        int N, float invN) {
    int t = blockIdx.x * 256 + threadIdx.x;
    int i = t / F;
    int j = t & (F - 1);
    if (i >= N) return;
    float sc = 1.0f, sh = 0.0f;
    if (BN) {
        float mu = stats[j] * invN;
        float var = fmaxf(stats[F + j] * invN - mu * mu, 0.0f);
        sc = rsqrtf(var + BN_EPS) * gw[j];
        sh = bw[j] - mu * sc;
    }
    int k = off[i], e = off[i + 1];
    float cnt = (float)(e - k + 1);
    float acc = (float)in[(size_t)i * F + j];
    for (; k + 4 <= e; k += 4) {
        int n0 = elist[k], n1 = elist[k + 1], n2 = elist[k + 2], n3 = elist[k + 3];
        float a0 = (float)in[(size_t)n0 * F + j];
        float a1 = (float)in[(size_t)n1 * F + j];
        float a2 = (float)in[(size_t)n2 * F + j];
        float a3 = (float)in[(size_t)n3 * F + j];
        acc += (a0 + a1) + (a2 + a3);
    }
    for (; k < e; k++) acc += (float)in[(size_t)elist[k] * F + j];
    if (BN) acc = fmaf(acc, sc, cnt * sh);
    agg[(size_t)i * F + j] = (f16)acc;
}

// ================= MFMA GEMM: Out = relu(A @ W + b), optional col stats =======
// A: [N,FIN] f16, W: [FIN,FOUT] f32 (converted to f16 frags in LDS),
// Out: [N,FOUT] of OutT (f16 or f32). One wave per 16-row stripe.
// mfma_f32_16x16x32_f16: A[m=lane&15][k=(lane>>4)*8+j], B[k][n=lane&15],
// C col=lane&15, row=(lane>>4)*4+reg  (N assumed % 16 == 0)
template<int FIN, int FOUT, bool STATS, typename OutT>
__global__ __launch_bounds__(256) void gemm_mfma(const f16* __restrict__ A,
        const float* __restrict__ W, const float* __restrict__ bias,
        OutT* __restrict__ Out, float* __restrict__ stats, int N) {
    constexpr int NS = FIN / 32;    // k-steps
    constexpr int NT = FOUT / 16;   // n-tiles
    __shared__ f16 Wl[NS * NT * 512];
    __shared__ float Bl[FOUT];
    __shared__ float Ss[STATS ? 2 * FOUT : 1];

    // stage W into frag-ordered f16 LDS
    for (int i = threadIdx.x; i < FIN * FOUT; i += 256) {
        int k = i / FOUT, n = i & (FOUT - 1);
        int s = k >> 5, kk = k & 31;
        int lane = (n & 15) | ((kk >> 3) << 4);
        int j = kk & 7;
        Wl[(((s * NT) + (n >> 4)) << 9) + (lane << 3) + j] = (f16)W[i];
    }
    if (threadIdx.x < FOUT) Bl[threadIdx.x] = bias[threadIdx.x];
    if (STATS) for (int i = threadIdx.x; i < 2 * FOUT; i += 256) Ss[i] = 0.0f;
    __syncthreads();

    const int wid = threadIdx.x >> 6;
    const int lane = threadIdx.x & 63;
    const int col = lane & 15;
    const int quad = lane >> 4;

    // all W frags into registers
    f16x8 Bf[NS][NT];
#pragma unroll
    for (int s = 0; s < NS; s++)
#pragma unroll
        for (int t = 0; t < NT; t++)
            Bf[s][t] = *(const f16x8*)&Wl[((s * NT + t) << 9) + (lane << 3)];

    float ls[NT], ls2[NT];
#pragma unroll
    for (int t = 0; t < NT; t++) { ls[t] = 0.0f; ls2[t] = 0.0f; }

    const int S = N >> 4;
    for (int sidx = blockIdx.x * 4 + wid; sidx < S; sidx += (int)gridDim.x * 4) {
        const int m0 = sidx << 4;
        const f16* a0 = A + (size_t)(m0 + col) * FIN + (quad << 3);
        f16x8 Af[NS];
#pragma unroll
        for (int s = 0; s < NS; s++) Af[s] = *(const f16x8*)(a0 + s * 32);
        f32x4 acc[NT];
#pragma unroll
        for (int t = 0; t < NT; t++) {
            float b = Bl[t * 16 + col];
            acc[t] = (f32x4){b, b, b, b};
        }
#pragma unroll
        for (int t = 0; t < NT; t++)
#pragma unroll
            for (int s = 0; s < NS; s++)
                acc[t] = __builtin_amdgcn_mfma_f32_16x16x32_f16(Af[s], Bf[s][t], acc[t], 0, 0, 0);
#pragma unroll
        for (int t = 0; t < NT; t++) {
            float v0 = fmaxf(acc[t][0], 0.0f);
            float v1 = fmaxf(acc[t][1], 0.0f);
            float v2 = fmaxf(acc[t][2], 0.0f);
            float v3 = fmaxf(acc[t][3], 0.0f);
            if (STATS) {
                ls[t]  += (v0 + v1) + (v2 + v3);
                ls2[t] += (v0 * v0 + v1 * v1) + (v2 * v2 + v3 * v3);
            }
            OutT* o = Out + (size_t)(m0 + quad * 4) * FOUT + t * 16 + col;
            o[0]        = (OutT)v0;
            o[FOUT]     = (OutT)v1;
            o[2 * FOUT] = (OutT)v2;
            o[3 * FOUT] = (OutT)v3;
        }
    }

    if (STATS) {
#pragma unroll
        for (int t = 0; t < NT; t++) {
            float s1 = ls[t], s2 = ls2[t];
            s1 += __shfl_xor(s1, 16); s1 += __shfl_xor(s1, 32);
            s2 += __shfl_xor(s2, 16); s2 += __shfl_xor(s2, 32);
            if (quad == 0) {
                atomicAdd(&Ss[t * 16 + col], s1);
                atomicAdd(&Ss[FOUT + t * 16 + col], s2);
            }
        }
        __syncthreads();
        for (int i = threadIdx.x; i < 2 * FOUT; i += 256) atomicAdd(&stats[i], Ss[i]);
    }
}

// ================= layer-3 BN + segmented pool (batch sorted) =================
__global__ __launch_bounds__(256) void bn_pool_kernel(const float* __restrict__ y,
        const float* __restrict__ stats, const float* __restrict__ gw,
        const float* __restrict__ bw, const int* __restrict__ batch,
        float* __restrict__ pool, int N, float invN) {
    constexpr int F = 32, CH = 64;
    int q = threadIdx.x >> 5;
    int j = threadIdx.x & 31;
    int r0 = (blockIdx.x * 8 + q) * CH;
    if (r0 >= N) return;
    int r1 = min(r0 + CH, N);
    float mu = stats[j] * invN;
    float var = fmaxf(stats[F + j] * invN - mu * mu, 0.0f);
    float sc = rsqrtf(var + BN_EPS) * gw[j];
    float sh = bw[j] - mu * sc;
    int curg = batch[r0];
    float acc = 0.0f;
    for (int r = r0; r < r1; r++) {
        int g = batch[r];
        if (g != curg) {
            atomicAdd(pool + (size_t)curg * 32 + j, acc);
            acc = 0.0f;
            curg = g;
        }
        acc = fmaf(y[(size_t)r * 32 + j], sc, sh + acc);
    }
    atomicAdd(pool + (size_t)curg * 32 + j, acc);
}

// ================= FC head =================
__global__ __launch_bounds__(128) void fc_kernel(const float* __restrict__ pool,
        const float* __restrict__ Wf1, const float* __restrict__ bf1,
        const float* __restrict__ Wf2, const float* __restrict__ bf2,
        const float* __restrict__ Wf3, const float* __restrict__ bf3,
        float* __restrict__ out) {
    __shared__ float zin[32];
    __shared__ float h1[128];
    __shared__ float h2[64];
    const int gidx = blockIdx.x;
    const int t = threadIdx.x;
    if (t < 32) zin[t] = pool[(size_t)gidx * 32 + t];
    __syncthreads();
    {
        float a = bf1[t];
        for (int k = 0; k < 32; k++) a = fmaf(zin[k], Wf1[k * 128 + t], a);
        h1[t] = fmaxf(a, 0.0f);
    }
    __syncthreads();
    if (t < 64) {
        float a = bf2[t];
        for (int k = 0; k < 128; k++) a = fmaf(h1[k], Wf2[k * 64 + t], a);
        h2[t] = fmaxf(a, 0.0f);
    }
    __syncthreads();
    if (t < 10) {
        float a = bf3[t];
        for (int k = 0; k < 64; k++) a = fmaf(h2[k], Wf3[k * 10 + t], a);
        out[(size_t)gidx * 10 + t] = a;
    }
}

extern "C" void kernel_launch(void* const* d_in, const int* in_sizes, int n_in,
                              void* d_out, int out_size, void* d_ws, size_t ws_size,
                              hipStream_t stream) {
    const float* x   = (const float*)d_in[0];
    const int*  ei   = (const int*)d_in[1];
    const int*  batch= (const int*)d_in[2];
    const float* W1a = (const float*)d_in[3];  const float* b1a = (const float*)d_in[4];
    const float* W1b = (const float*)d_in[5];  const float* b1b = (const float*)d_in[6];
    const float* g1  = (const float*)d_in[7];  const float* be1 = (const float*)d_in[8];
    const float* W2a = (const float*)d_in[9];  const float* b2a = (const float*)d_in[10];
    const float* W2b = (const float*)d_in[11]; const float* b2b = (const float*)d_in[12];
    const float* g2  = (const float*)d_in[13]; const float* be2 = (const float*)d_in[14];
    const float* W3a = (const float*)d_in[15]; const float* b3a = (const float*)d_in[16];
    const float* W3b = (const float*)d_in[17]; const float* b3b = (const float*)d_in[18];
    const float* g3  = (const float*)d_in[19]; const float* be3 = (const float*)d_in[20];
    const float* Wf1 = (const float*)d_in[21]; const float* bf1 = (const float*)d_in[22];
    const float* Wf2 = (const float*)d_in[23]; const float* bf2 = (const float*)d_in[24];
    const float* Wf3 = (const float*)d_in[25]; const float* bf3 = (const float*)d_in[26];

    const int N = in_sizes[2];
    const int E = in_sizes[1] / 2;
    const int G = out_size / 10;
    const int* src = ei;
    const int* dst = ei + E;

    // ---- dedicated ws regions ----
    float* B0   = (float*)d_ws;              // N*128 f32 worth of space
    float* B1   = B0 + (size_t)N * 128;      // N*128 f32 worth of space
    float* pool = B1 + (size_t)N * 128;      // G*32
    float* st1  = pool + (size_t)G * 32;     // 256 each
    float* st2  = st1 + 256;
    float* st3  = st2 + 256;
    int* off    = (int*)(st3 + 256);         // N+1
    int* bsum   = off + (N + 1);             // 128
    int* elist  = bsum + 128;                // E

    // ---- aliases (stream-order safe; f16 = half-width of the f32 regions) ----
    int* deg   = (int*)B0;                   // N ints   (CSR phase)
    int* rank  = (int*)B0 + N;               // E ints   (CSR phase)
    f16* xh    = (f16*)B1;                   // N*64
    f16* A1    = (f16*)B1 + (size_t)N * 64;  // N*64
    f16* H1    = (f16*)B0;                   // N*128 (after CSR phase)
    f16* Y1    = (f16*)B1;                   // N*128 (xh,A1 dead)
    f16* A2    = (f16*)B0;                   // N*128 (H1 dead)
    f16* H2    = (f16*)B1;                   // N*64  (Y1 dead)
    f16* Y2    = (f16*)B0;                   // N*64  (A2 dead)
    f16* A3    = (f16*)B1;                   // N*64  (H2 dead)
    f16* H3    = (f16*)B0 + (size_t)N * 64;  // N*32  (keep Y2 region clear)
    float* Y3  = B1;                         // N*32 f32 (A3 dead)

    hipMemsetAsync(pool, 0, ((size_t)G * 32 + 768) * sizeof(float), stream);
    hipMemsetAsync(deg, 0, (size_t)N * sizeof(int), stream);

    const float invN = 1.0f / (float)N;
    const int NB = (N + 1023) / 1024;
    const int GG = 640;  // gemm blocks (4 waves each, grid-stride over N/16 stripes)

    // ---- x -> f16 ----
    conv_kernel<<<(N * 16 + 255) / 256, 256, 0, stream>>>((const float4*)x, (f16x4*)xh, N * 16);

    // ---- CSR build ----
    hist_kernel<<<(E + 255) / 256, 256, 0, stream>>>(dst, deg, rank, E);
    scan_block<<<NB, 1024, 0, stream>>>(deg, off, bsum, N);
    scan_bsum<<<1, 128, 0, stream>>>(bsum, NB);
    scan_finish<<<NB, 1024, 0, stream>>>(off, bsum, N);
    fill_kernel<<<(E + 255) / 256, 256, 0, stream>>>(src, dst, rank, off, elist, E);

    // ---- Layer 1 ----
    gather_kernel<64, false><<<(N * 64 + 255) / 256, 256, 0, stream>>>(off, elist, xh, A1, nullptr, nullptr, nullptr, N, invN);
    gemm_mfma<64, 128, false, f16><<<GG, 256, 0, stream>>>(A1, W1a, b1a, H1, nullptr, N);
    gemm_mfma<128, 128, true, f16><<<GG, 256, 0, stream>>>(H1, W1b, b1b, Y1, st1, N);

    // ---- Layer 2 ----
    gather_kernel<128, true><<<(N * 128 + 255) / 256, 256, 0, stream>>>(off, elist, Y1, A2, st1, g1, be1, N, invN);
    gemm_mfma<128, 64, false, f16><<<GG, 256, 0, stream>>>(A2, W2a, b2a, H2, nullptr, N);
    gemm_mfma<64, 64, true, f16><<<GG, 256, 0, stream>>>(H2, W2b, b2b, Y2, st2, N);

    // ---- Layer 3 ----
    gather_kernel<64, true><<<(N * 64 + 255) / 256, 256, 0, stream>>>(off, elist, Y2, A3, st2, g2, be2, N, invN);
    gemm_mfma<64, 32, false, f16><<<GG, 256, 0, stream>>>(A3, W3a, b3a, H3, nullptr, N);
    gemm_mfma<32, 32, true, float><<<GG, 256, 0, stream>>>(H3, W3b, b3b, Y3, st3, N);

    // ---- BN3 + segmented pool ----
    bn_pool_kernel<<<(N + 511) / 512, 256, 0, stream>>>(Y3, st3, g3, be3, batch, pool, N, invN);

    // ---- pooled MLP head ----
    fc_kernel<<<G, 128, 0, stream>>>(pool, Wf1, bf1, Wf2, bf2, Wf3, bf3, (float*)d_out);
}

// Round 6
// 692.230 us; speedup vs baseline: 16.6806x; 1.2302x over previous
//
#include <hip/hip_runtime.h>

#define BN_EPS 1e-5f

typedef _Float16 f16;
typedef _Float16 f16x8 __attribute__((ext_vector_type(8)));
typedef _Float16 f16x4 __attribute__((ext_vector_type(4)));
typedef float f32x4 __attribute__((ext_vector_type(4)));

// ================= x -> f16 convert =================
__global__ __launch_bounds__(256) void conv_kernel(const float4* __restrict__ in,
        f16x4* __restrict__ out, int n4) {
    int i = blockIdx.x * 256 + threadIdx.x;
    if (i < n4) {
        float4 v = in[i];
        f16x4 o;
        o.x = (f16)v.x; o.y = (f16)v.y; o.z = (f16)v.z; o.w = (f16)v.w;
        out[i] = o;
    }
}

// ================= CSR build =================
__global__ __launch_bounds__(256) void hist_kernel(const int* __restrict__ dst,
        int* __restrict__ deg, int* __restrict__ rank, int E) {
    int e = blockIdx.x * 256 + threadIdx.x;
    if (e < E) rank[e] = atomicAdd(&deg[dst[e]], 1);
}

__global__ __launch_bounds__(1024) void scan_block(const int* __restrict__ deg,
        int* __restrict__ off, int* __restrict__ bsum, int N) {
    __shared__ int sh[1024];
    int g = blockIdx.x * 1024 + threadIdx.x;
    int v = (g < N) ? deg[g] : 0;
    sh[threadIdx.x] = v;
    __syncthreads();
    for (int d = 1; d < 1024; d <<= 1) {
        int t = (threadIdx.x >= d) ? sh[threadIdx.x - d] : 0;
        __syncthreads();
        sh[threadIdx.x] += t;
        __syncthreads();
    }
    if (g < N) off[g + 1] = sh[threadIdx.x];
    if (threadIdx.x == 1023) bsum[blockIdx.x] = sh[1023];
    if (g == 0) off[0] = 0;
}

__global__ __launch_bounds__(128) void scan_bsum(int* __restrict__ bsum, int nb) {
    __shared__ int sh[128];
    int v = (threadIdx.x < nb) ? bsum[threadIdx.x] : 0;
    sh[threadIdx.x] = v;
    __syncthreads();
    for (int d = 1; d < 128; d <<= 1) {
        int t = (threadIdx.x >= d) ? sh[threadIdx.x - d] : 0;
        __syncthreads();
        sh[threadIdx.x] += t;
        __syncthreads();
    }
    if (threadIdx.x < nb) bsum[threadIdx.x] = sh[threadIdx.x] - v;  // exclusive
}

__global__ __launch_bounds__(1024) void scan_finish(int* __restrict__ off,
        const int* __restrict__ bsum, int N) {
    int g = blockIdx.x * 1024 + threadIdx.x;
    if (g < N) off[g + 1] += bsum[blockIdx.x];
}

__global__ __launch_bounds__(256) void fill_kernel(const int* __restrict__ src,
        const int* __restrict__ dst, const int* __restrict__ rank,
        const int* __restrict__ off, int* __restrict__ elist, int E) {
    int e = blockIdx.x * 256 + threadIdx.x;
    if (e < E) elist[off[dst[e]] + rank[e]] = src[e];
}

// ================= vectorized gather (f16x4 per lane) =========================
// AFFINE==false: out[i] = in[i] + sum_{s in nbrs} in[s]
// AFFINE==true : out[i] = relu( acc + cnt*v + b ),  cnt = deg+1
template<int F, bool AFFINE>
__global__ __launch_bounds__(256) void gather_v(const int* __restrict__ off,
        const int* __restrict__ elist, const f16* __restrict__ in,
        f16* __restrict__ out, const float* __restrict__ v,
        const float* __restrict__ bias, int N) {
    constexpr int TPN = F / 4;           // threads per node
    constexpr int NPB = 256 / TPN;       // nodes per block
    const int i = blockIdx.x * NPB + threadIdx.x / TPN;
    const int l = threadIdx.x & (TPN - 1);
    if (i >= N) return;
    const int j0 = l * 4;
    f16x4 s = ((const f16x4*)(in + (size_t)i * F))[l];
    float a0 = (float)s.x, a1 = (float)s.y, a2 = (float)s.z, a3 = (float)s.w;
    int k = off[i], e = off[i + 1];
    const float cnt = (float)(e - k + 1);
    for (; k + 4 <= e; k += 4) {
        int n0 = elist[k], n1 = elist[k + 1], n2 = elist[k + 2], n3 = elist[k + 3];
        f16x4 p0 = ((const f16x4*)(in + (size_t)n0 * F))[l];
        f16x4 p1 = ((const f16x4*)(in + (size_t)n1 * F))[l];
        f16x4 p2 = ((const f16x4*)(in + (size_t)n2 * F))[l];
        f16x4 p3 = ((const f16x4*)(in + (size_t)n3 * F))[l];
        a0 += ((float)p0.x + (float)p1.x) + ((float)p2.x + (float)p3.x);
        a1 += ((float)p0.y + (float)p1.y) + ((float)p2.y + (float)p3.y);
        a2 += ((float)p0.z + (float)p1.z) + ((float)p2.z + (float)p3.z);
        a3 += ((float)p0.w + (float)p1.w) + ((float)p2.w + (float)p3.w);
    }
    for (; k < e; k++) {
        f16x4 p = ((const f16x4*)(in + (size_t)elist[k] * F))[l];
        a0 += (float)p.x; a1 += (float)p.y; a2 += (float)p.z; a3 += (float)p.w;
    }
    if (AFFINE) {
        float4 vv = *(const float4*)(v + j0);
        float4 bb = *(const float4*)(bias + j0);
        a0 = fmaxf(fmaf(cnt, vv.x, a0 + bb.x), 0.0f);
        a1 = fmaxf(fmaf(cnt, vv.y, a1 + bb.y), 0.0f);
        a2 = fmaxf(fmaf(cnt, vv.z, a2 + bb.z), 0.0f);
        a3 = fmaxf(fmaf(cnt, vv.w, a3 + bb.w), 0.0f);
    }
    f16x4 o;
    o.x = (f16)a0; o.y = (f16)a1; o.z = (f16)a2; o.w = (f16)a3;
    ((f16x4*)(out + (size_t)i * F))[l] = o;
}

// ================= prep: v[j] = sum_k sh[k] * W[k][j] =========================
__global__ __launch_bounds__(64) void prep_kernel(const float* __restrict__ W,
        const float* __restrict__ stats, const float* __restrict__ g,
        const float* __restrict__ be, float* __restrict__ v,
        int FIN, int FOUT, float invN) {
    int j = threadIdx.x;
    if (j >= FOUT) return;
    float acc = 0.0f;
    for (int k = 0; k < FIN; k++) {
        float mu = stats[k] * invN;
        float var = fmaxf(stats[FIN + k] * invN - mu * mu, 0.0f);
        float sc = rsqrtf(var + BN_EPS) * g[k];
        float sh = be[k] - mu * sc;
        acc = fmaf(sh, W[(size_t)k * FOUT + j], acc);
    }
    v[j] = acc;
}

// ================= MFMA GEMM ==================================================
// Out = [relu]( A @ (diag(sc)? W) + (bias?) ), optional col stats of output.
// A: [N,FIN] f16, W: [FIN,FOUT] f32. One wave per 16-row stripe. N % 16 == 0.
template<int FIN, int FOUT, bool STATS, bool RELU, bool BIAS, bool BNW, typename OutT>
__global__ __launch_bounds__(256) void gemm_mfma(const f16* __restrict__ A,
        const float* __restrict__ W, const float* __restrict__ bias,
        OutT* __restrict__ Out, float* __restrict__ stats,
        const float* __restrict__ bnstats, const float* __restrict__ bng,
        float invN, int N) {
    constexpr int NS = FIN / 32;    // k-steps
    constexpr int NT = FOUT / 16;   // n-tiles
    __shared__ f16 Wl[NS * NT * 512];
    __shared__ float Bl[BIAS ? FOUT : 1];
    __shared__ float Ss[STATS ? 2 * FOUT : 1];
    __shared__ float Scs[BNW ? FIN : 1];

    if (BNW) {
        for (int k = threadIdx.x; k < FIN; k += 256) {
            float mu = bnstats[k] * invN;
            float var = fmaxf(bnstats[FIN + k] * invN - mu * mu, 0.0f);
            Scs[k] = rsqrtf(var + BN_EPS) * bng[k];
        }
        __syncthreads();
    }
    // stage W into frag-ordered f16 LDS
    for (int i = threadIdx.x; i < FIN * FOUT; i += 256) {
        int k = i / FOUT, n = i & (FOUT - 1);
        int s = k >> 5, kk = k & 31;
        int lane = (n & 15) | ((kk >> 3) << 4);
        int j = kk & 7;
        float wv = W[i];
        if (BNW) wv *= Scs[k];
        Wl[(((s * NT) + (n >> 4)) << 9) + (lane << 3) + j] = (f16)wv;
    }
    if (BIAS && threadIdx.x < FOUT) Bl[threadIdx.x] = bias[threadIdx.x];
    if (STATS) for (int i = threadIdx.x; i < 2 * FOUT; i += 256) Ss[i] = 0.0f;
    __syncthreads();

    const int wid = threadIdx.x >> 6;
    const int lane = threadIdx.x & 63;
    const int col = lane & 15;
    const int quad = lane >> 4;

    f16x8 Bf[NS][NT];
#pragma unroll
    for (int s = 0; s < NS; s++)
#pragma unroll
        for (int t = 0; t < NT; t++)
            Bf[s][t] = *(const f16x8*)&Wl[((s * NT + t) << 9) + (lane << 3)];

    float ls[NT], ls2[NT];
#pragma unroll
    for (int t = 0; t < NT; t++) { ls[t] = 0.0f; ls2[t] = 0.0f; }

    const int S = N >> 4;
    for (int sidx = blockIdx.x * 4 + wid; sidx < S; sidx += (int)gridDim.x * 4) {
        const int m0 = sidx << 4;
        const f16* a0 = A + (size_t)(m0 + col) * FIN + (quad << 3);
        f16x8 Af[NS];
#pragma unroll
        for (int s = 0; s < NS; s++) Af[s] = *(const f16x8*)(a0 + s * 32);
        f32x4 acc[NT];
#pragma unroll
        for (int t = 0; t < NT; t++) {
            float b = BIAS ? Bl[t * 16 + col] : 0.0f;
            acc[t] = (f32x4){b, b, b, b};
        }
#pragma unroll
        for (int t = 0; t < NT; t++)
#pragma unroll
            for (int s = 0; s < NS; s++)
                acc[t] = __builtin_amdgcn_mfma_f32_16x16x32_f16(Af[s], Bf[s][t], acc[t], 0, 0, 0);
#pragma unroll
        for (int t = 0; t < NT; t++) {
            float v0 = acc[t][0], v1 = acc[t][1], v2 = acc[t][2], v3 = acc[t][3];
            if (RELU) {
                v0 = fmaxf(v0, 0.0f); v1 = fmaxf(v1, 0.0f);
                v2 = fmaxf(v2, 0.0f); v3 = fmaxf(v3, 0.0f);
            }
            if (STATS) {
                ls[t]  += (v0 + v1) + (v2 + v3);
                ls2[t] += (v0 * v0 + v1 * v1) + (v2 * v2 + v3 * v3);
            }
            OutT* o = Out + (size_t)(m0 + quad * 4) * FOUT + t * 16 + col;
            o[0]        = (OutT)v0;
            o[FOUT]     = (OutT)v1;
            o[2 * FOUT] = (OutT)v2;
            o[3 * FOUT] = (OutT)v3;
        }
    }

    if (STATS) {
#pragma unroll
        for (int t = 0; t < NT; t++) {
            float s1 = ls[t], s2 = ls2[t];
            s1 += __shfl_xor(s1, 16); s1 += __shfl_xor(s1, 32);
            s2 += __shfl_xor(s2, 16); s2 += __shfl_xor(s2, 32);
            if (quad == 0) {
                atomicAdd(&Ss[t * 16 + col], s1);
                atomicAdd(&Ss[FOUT + t * 16 + col], s2);
            }
        }
        __syncthreads();
        for (int i = threadIdx.x; i < 2 * FOUT; i += 256) atomicAdd(&stats[i], Ss[i]);
    }
}

// ================= layer-3 BN + segmented pool (batch sorted) =================
__global__ __launch_bounds__(256) void bn_pool_kernel(const float* __restrict__ y,
        const float* __restrict__ stats, const float* __restrict__ gw,
        const float* __restrict__ bw, const int* __restrict__ batch,
        float* __restrict__ pool, int N, float invN) {
    constexpr int F = 32, CH = 64;
    int q = threadIdx.x >> 5;
    int j = threadIdx.x & 31;
    int r0 = (blockIdx.x * 8 + q) * CH;
    if (r0 >= N) return;
    int r1 = min(r0 + CH, N);
    float mu = stats[j] * invN;
    float var = fmaxf(stats[F + j] * invN - mu * mu, 0.0f);
    float sc = rsqrtf(var + BN_EPS) * gw[j];
    float sh = bw[j] - mu * sc;
    int curg = batch[r0];
    float acc = 0.0f;
    for (int r = r0; r < r1; r++) {
        int g = batch[r];
        if (g != curg) {
            atomicAdd(pool + (size_t)curg * 32 + j, acc);
            acc = 0.0f;
            curg = g;
        }
        acc = fmaf(y[(size_t)r * 32 + j], sc, sh + acc);
    }
    atomicAdd(pool + (size_t)curg * 32 + j, acc);
}

// ================= FC head =================
__global__ __launch_bounds__(128) void fc_kernel(const float* __restrict__ pool,
        const float* __restrict__ Wf1, const float* __restrict__ bf1,
        const float* __restrict__ Wf2, const float* __restrict__ bf2,
        const float* __restrict__ Wf3, const float* __restrict__ bf3,
        float* __restrict__ out) {
    __shared__ float zin[32];
    __shared__ float h1[128];
    __shared__ float h2[64];
    const int gidx = blockIdx.x;
    const int t = threadIdx.x;
    if (t < 32) zin[t] = pool[(size_t)gidx * 32 + t];
    __syncthreads();
    {
        float a = bf1[t];
        for (int k = 0; k < 32; k++) a = fmaf(zin[k], Wf1[k * 128 + t], a);
        h1[t] = fmaxf(a, 0.0f);
    }
    __syncthreads();
    if (t < 64) {
        float a = bf2[t];
        for (int k = 0; k < 128; k++) a = fmaf(h1[k], Wf2[k * 64 + t], a);
        h2[t] = fmaxf(a, 0.0f);
    }
    __syncthreads();
    if (t < 10) {
        float a = bf3[t];
        for (int k = 0; k < 64; k++) a = fmaf(h2[k], Wf3[k * 10 + t], a);
        out[(size_t)gidx * 10 + t] = a;
    }
}

extern "C" void kernel_launch(void* const* d_in, const int* in_sizes, int n_in,
                              void* d_out, int out_size, void* d_ws, size_t ws_size,
                              hipStream_t stream) {
    const float* x   = (const float*)d_in[0];
    const int*  ei   = (const int*)d_in[1];
    const int*  batch= (const int*)d_in[2];
    const float* W1a = (const float*)d_in[3];  const float* b1a = (const float*)d_in[4];
    const float* W1b = (const float*)d_in[5];  const float* b1b = (const float*)d_in[6];
    const float* g1  = (const float*)d_in[7];  const float* be1 = (const float*)d_in[8];
    const float* W2a = (const float*)d_in[9];  const float* b2a = (const float*)d_in[10];
    const float* W2b = (const float*)d_in[11]; const float* b2b = (const float*)d_in[12];
    const float* g2  = (const float*)d_in[13]; const float* be2 = (const float*)d_in[14];
    const float* W3a = (const float*)d_in[15]; const float* b3a = (const float*)d_in[16];
    const float* W3b = (const float*)d_in[17]; const float* b3b = (const float*)d_in[18];
    const float* g3  = (const float*)d_in[19]; const float* be3 = (const float*)d_in[20];
    const float* Wf1 = (const float*)d_in[21]; const float* bf1 = (const float*)d_in[22];
    const float* Wf2 = (const float*)d_in[23]; const float* bf2 = (const float*)d_in[24];
    const float* Wf3 = (const float*)d_in[25]; const float* bf3 = (const float*)d_in[26];

    const int N = in_sizes[2];
    const int E = in_sizes[1] / 2;
    const int G = out_size / 10;
    const int* src = ei;
    const int* dst = ei + E;

    // ---- dedicated ws regions ----
    float* B0   = (float*)d_ws;              // N*128 f32 worth (= N*256 f16)
    float* B1   = B0 + (size_t)N * 128;
    float* pool = B1 + (size_t)N * 128;      // G*32
    float* st1  = pool + (size_t)G * 32;     // 256 each
    float* st2  = st1 + 256;
    float* st3  = st2 + 256;
    int* off    = (int*)(st3 + 256);         // N+1
    int* bsum   = off + (N + 1);             // 128
    int* elist  = bsum + 128;                // E
    float* v2   = (float*)(elist + E);       // 64
    float* v3   = v2 + 64;                   // 32

    // ---- aliases (stream-order safe) ----
    int* deg   = (int*)B1;                    // N ints   (CSR phase)
    int* rank  = (int*)B1 + N;                // E ints   (CSR phase)
    f16* xh    = (f16*)B0;                    // N*64  [B0 slot A: 0..N*64)
    f16* A1    = (f16*)B1;                    // N*64  [B1 slot A] (deg/rank dead)
    f16* H1    = (f16*)B0 + (size_t)N * 64;   // N*128 [B0 slot B: N*64..N*192)
    f16* Y1    = (f16*)B1 + (size_t)N * 64;   // N*128 [B1 slot B]
    f16* Z1    = (f16*)B0;                    // N*64  [B0 slot A] (xh dead)
    f16* H2    = (f16*)B1;                    // N*64  [B1 slot A] (A1 dead)
    f16* Y2    = (f16*)B0 + (size_t)N * 64;   // N*64  [B0 slot B] (H1 dead)
    f16* Z2    = (f16*)B0;                    // N*32  [B0 slot A] (Z1 dead)
    f16* H3    = (f16*)B1;                    // N*32  [B1 slot A] (H2 dead)
    float* Y3  = B1 + (size_t)N * 64;         // N*32 f32 [B1 slot B] (Y1 dead)

    hipMemsetAsync(pool, 0, ((size_t)G * 32 + 768) * sizeof(float), stream);
    hipMemsetAsync(deg, 0, (size_t)N * sizeof(int), stream);

    const float invN = 1.0f / (float)N;
    const int NB = (N + 1023) / 1024;
    const int GG = 640;

    // ---- x -> f16 ----
    conv_kernel<<<(N * 16 + 255) / 256, 256, 0, stream>>>((const float4*)x, (f16x4*)xh, N * 16);

    // ---- CSR build ----
    hist_kernel<<<(E + 255) / 256, 256, 0, stream>>>(dst, deg, rank, E);
    scan_block<<<NB, 1024, 0, stream>>>(deg, off, bsum, N);
    scan_bsum<<<1, 128, 0, stream>>>(bsum, NB);
    scan_finish<<<NB, 1024, 0, stream>>>(off, bsum, N);
    fill_kernel<<<(E + 255) / 256, 256, 0, stream>>>(src, dst, rank, off, elist, E);

    // ---- Layer 1: gather(x,64) -> gemm 64->128 relu -> gemm 128->128 relu+stats
    gather_v<64, false><<<(N + 15) / 16, 256, 0, stream>>>(off, elist, xh, A1, nullptr, nullptr, N);
    gemm_mfma<64, 128, false, true, true, false, f16><<<GG, 256, 0, stream>>>(A1, W1a, b1a, H1, nullptr, nullptr, nullptr, invN, N);
    gemm_mfma<128, 128, true, true, true, false, f16><<<GG, 256, 0, stream>>>(H1, W1b, b1b, Y1, st1, nullptr, nullptr, invN, N);

    // ---- Layer 2 (commuted): Z1 = Y1 @ diag(sc1) W2a; gather(Z1,64)+affine+relu -> H2
    prep_kernel<<<1, 64, 0, stream>>>(W2a, st1, g1, be1, v2, 128, 64, invN);
    gemm_mfma<128, 64, false, false, false, true, f16><<<GG, 256, 0, stream>>>(Y1, W2a, nullptr, Z1, nullptr, st1, g1, invN, N);
    gather_v<64, true><<<(N + 15) / 16, 256, 0, stream>>>(off, elist, Z1, H2, v2, b2a, N);
    gemm_mfma<64, 64, true, true, true, false, f16><<<GG, 256, 0, stream>>>(H2, W2b, b2b, Y2, st2, nullptr, nullptr, invN, N);

    // ---- Layer 3 (commuted): Z2 = Y2 @ diag(sc2) W3a; gather(Z2,32)+affine+relu -> H3
    prep_kernel<<<1, 64, 0, stream>>>(W3a, st2, g2, be2, v3, 64, 32, invN);
    gemm_mfma<64, 32, false, false, false, true, f16><<<GG, 256, 0, stream>>>(Y2, W3a, nullptr, Z2, nullptr, st2, g2, invN, N);
    gather_v<32, true><<<(N + 31) / 32, 256, 0, stream>>>(off, elist, Z2, H3, v3, b3a, N);
    gemm_mfma<32, 32, true, true, true, false, float><<<GG, 256, 0, stream>>>(H3, W3b, b3b, Y3, st3, nullptr, nullptr, invN, N);

    // ---- BN3 + segmented pool ----
    bn_pool_kernel<<<(N + 511) / 512, 256, 0, stream>>>(Y3, st3, g3, be3, batch, pool, N, invN);

    // ---- pooled MLP head ----
    fc_kernel<<<G, 128, 0, stream>>>(pool, Wf1, bf1, Wf2, bf2, Wf3, bf3, (float*)d_out);
}